// Round 8
// baseline (114.144 us; speedup 1.0000x reference)
//
#include <hip/hip_runtime.h>

#define NPTS 8192
#define BATCH 4
#define BLOCK 256
#define NQ 8                   // queries per thread — this round's ONE change (R7 had 4)
#define QPB (BLOCK * NQ)       // 2048 queries per block
#define QBLOCKS (NPTS / QPB)   // 4
#define SEGS 32
#define SEGLEN (NPTS / SEGS)   // 256 targets per segment

// ---------------------------------------------------------------------------
// chamfer: grid (QBLOCKS*SEGS, BATCH, 2). Expanded form d = |p|^2+|q|^2-2p.q.
// LDS: tgtA[j]={x0,x1,y0,y1}, tgtB[j]={z0,z1,|q0|^2,|q1|^2} (paired targets).
// Per 2 targets per wave: 2 ds_read_b128 + NQ*(6 fma + 1 min3).
// NQ=8: VALU 112 cyc vs per-CU LDS ~96 cyc per iteration -> VALU-bound
// (NQ=4 measured 44.5 us, LDS-pipe-bound per the R3 model).
// Partial mins merged via atomicMin on float bits (distances clamped >= 0,
// so uint order == float order); mins initialized to 0xFFFFFFFF by memset.
// ---------------------------------------------------------------------------
__global__ __launch_bounds__(256) void chamfer_kernel(
    const float* __restrict__ x, const float* __restrict__ y,
    unsigned* __restrict__ mins) {
    __shared__ float4 tgtA[SEGLEN / 2];
    __shared__ float4 tgtB[SEGLEN / 2];

    const int dir = blockIdx.z;
    const int b = blockIdx.y;
    const int seg = blockIdx.x & (SEGS - 1);
    const int qb = blockIdx.x >> 5;  // / SEGS

    const float* pts = dir ? y : x;  // query set
    const float* oth = dir ? x : y;  // target set

    // stage one segment: one point per thread (SEGLEN == BLOCK)
    {
        const int p = threadIdx.x;
        const float* q = oth + ((size_t)b * NPTS + seg * SEGLEN + p) * 3;
        const float qx = q[0], qy = q[1], qz = q[2];
        const float sq = fmaf(qz, qz, fmaf(qy, qy, qx * qx));
        float* A = (float*)tgtA;
        float* Bv = (float*)tgtB;
        const int pi = p >> 1, par = p & 1;
        A[pi * 4 + par] = qx;
        A[pi * 4 + 2 + par] = qy;
        Bv[pi * 4 + par] = qz;
        Bv[pi * 4 + 2 + par] = sq;
    }

    // query points -> registers (-2*p components; |p|^2 folded in at the end)
    float m2x[NQ], m2y[NQ], m2z[NQ], sp[NQ], best[NQ];
    const int qbase = b * NPTS + qb * QPB + (int)threadIdx.x;
#pragma unroll
    for (int k = 0; k < NQ; ++k) {
        const float* p = pts + (size_t)(qbase + k * BLOCK) * 3;
        const float px = p[0], py = p[1], pz = p[2];
        m2x[k] = -2.0f * px;
        m2y[k] = -2.0f * py;
        m2z[k] = -2.0f * pz;
        sp[k] = fmaf(pz, pz, fmaf(py, py, px * px));
        best[k] = 3.0e38f;
    }

    __syncthreads();

#pragma unroll 2
    for (int j = 0; j < SEGLEN / 2; ++j) {
        const float4 A = tgtA[j];
        const float4 Bv = tgtB[j];
#pragma unroll
        for (int k = 0; k < NQ; ++k) {
            float d0 = fmaf(m2x[k], A.x, Bv.z);   // x0, sq0
            d0 = fmaf(m2y[k], A.z, d0);           // y0
            d0 = fmaf(m2z[k], Bv.x, d0);          // z0
            float d1 = fmaf(m2x[k], A.y, Bv.w);   // x1, sq1
            d1 = fmaf(m2y[k], A.w, d1);           // y1
            d1 = fmaf(m2z[k], Bv.y, d1);          // z1
            best[k] = fminf(fminf(best[k], d0), d1);  // v_min3_f32
        }
    }

    unsigned* om = mins + (size_t)(dir * BATCH + b) * NPTS + qb * QPB + threadIdx.x;
#pragma unroll
    for (int k = 0; k < NQ; ++k) {
        const float d = fmaxf(sp[k] + best[k], 0.0f);  // >=0: uint order == float order
        atomicMin(&om[k * BLOCK], __float_as_uint(d));
    }
}

// ---------------------------------------------------------------------------
// finalize: 64 blocks x 256 threads (R7-proven). Each block sums a 4 KB
// slice of mins (uint4, coalesced), reduces, atomicAdds partial * 1/(B*N)
// into out[0] (pre-zeroed). Block 0 / thread 0 adds the regularizer.
// ---------------------------------------------------------------------------
__global__ __launch_bounds__(256) void finalize_kernel(
    const unsigned* __restrict__ mins, const float* __restrict__ R,
    const float* __restrict__ S, const float* __restrict__ t,
    const float* __restrict__ R_gt, const float* __restrict__ S_gt,
    const float* __restrict__ t_gt, float* __restrict__ out) {
    const uint4* m4 = (const uint4*)mins;  // 2*B*N/4 = 16384 uint4s
    const int gid = blockIdx.x * 256 + (int)threadIdx.x;  // 0..16383
    const uint4 u = m4[gid];
    float v = (__uint_as_float(u.x) + __uint_as_float(u.y) +
               __uint_as_float(u.z) + __uint_as_float(u.w)) *
              (1.0f / (BATCH * NPTS));

    if (gid == 0) {
        float acc = 0.0f;
        for (int b = 0; b < BATCH; ++b)
            for (int i = 0; i < 3; ++i)
                for (int k = 0; k < 3; ++k) {
                    float s = 0.0f;
                    for (int j = 0; j < 3; ++j)
                        s += R_gt[b * 9 + j * 3 + i] * R[b * 9 + j * 3 + k];
                    s -= (i == k) ? 1.0f : 0.0f;
                    acc += s * s;
                }
        for (int d = 0; d < 3; ++d)  // jnp.diagonal(S, axis1=0, axis2=1)
            for (int a = 0; a < 3; ++a) {
                const float diff = S[d * 9 + d * 3 + a] - S_gt[d * 9 + d * 3 + a];
                acc += diff * diff;
            }
        for (int b = 0; b < BATCH; ++b)
            for (int k = 0; k < 3; ++k) {
                const float diff = t[b * 3 + k] - t_gt[b * 3 + k];
                acc += diff * diff;
            }
        v += acc;
    }

    // block reduction: 4 waves of 64
    for (int off = 32; off; off >>= 1) v += __shfl_down(v, off, 64);
    __shared__ float wsum[4];
    const int lane = threadIdx.x & 63;
    const int wave = threadIdx.x >> 6;
    if (lane == 0) wsum[wave] = v;
    __syncthreads();
    if (wave == 0) {
        v = (lane < 4) ? wsum[lane] : 0.0f;
        for (int off = 2; off; off >>= 1) v += __shfl_down(v, off, 64);
        if (lane == 0) atomicAdd(out, v);
    }
}

extern "C" void kernel_launch(void* const* d_in, const int* in_sizes, int n_in,
                              void* d_out, int out_size, void* d_ws, size_t ws_size,
                              hipStream_t stream) {
    const float* x    = (const float*)d_in[0];
    const float* y    = (const float*)d_in[1];
    const float* R    = (const float*)d_in[2];
    const float* S    = (const float*)d_in[3];
    const float* t    = (const float*)d_in[4];
    const float* R_gt = (const float*)d_in[5];
    const float* S_gt = (const float*)d_in[6];
    const float* t_gt = (const float*)d_in[7];
    float* out = (float*)d_out;
    unsigned* mins = (unsigned*)d_ws;  // 2*B*N uints = 256 KiB

    // init mins to 0xFFFFFFFF (uint max) for atomicMin; zero the scalar out.
    hipMemsetAsync(mins, 0xFF, (size_t)2 * BATCH * NPTS * sizeof(unsigned), stream);
    hipMemsetAsync(out, 0, sizeof(float), stream);

    chamfer_kernel<<<dim3(QBLOCKS * SEGS, BATCH, 2), dim3(BLOCK), 0, stream>>>(x, y, mins);

    finalize_kernel<<<dim3(2 * BATCH * NPTS / 4 / 256), dim3(BLOCK), 0, stream>>>(
        mins, R, S, t, R_gt, S_gt, t_gt, out);
}

// Round 9
// 108.896 us; speedup vs baseline: 1.0482x; 1.0482x over previous
//
#include <hip/hip_runtime.h>

#define NPTS 8192
#define BATCH 4
#define BLOCK 256
#define NQ 8                   // queries per thread
#define QPB (BLOCK * NQ)       // 2048 queries per block
#define QBLOCKS (NPTS / QPB)   // 4
#define SEGS 64                // (R8 had 32) -> 2048 blocks, 8 blocks/CU
#define SEG_SHIFT 6
#define SEGLEN (NPTS / SEGS)   // 128 targets per segment

typedef float v2f __attribute__((ext_vector_type(2)));

// ---------------------------------------------------------------------------
// chamfer: grid (QBLOCKS*SEGS, BATCH, 2). Expanded form d = |p|^2+|q|^2-2p.q.
// LDS: tgtA[j]={x0,x1,y0,y1}, tgtB[j]={z0,z1,|q0|^2,|q1|^2} (paired targets)
// -> pairs are VGPR-pair-aligned off ds_read_b128, enabling v_pk_fma_f32.
// Per 2 targets per query: 3 pk_fma + 1 min3 (was 6 fma + 1 min3).
// This round tests issue-limited (expect ~29 us) vs fp32-ALU-datapath-limited
// (expect unchanged ~45 us).
// Partial mins merged via atomicMin on float bits (distances clamped >= 0,
// so uint order == float order); mins initialized to 0xFFFFFFFF by memset.
// ---------------------------------------------------------------------------
__global__ __launch_bounds__(256) void chamfer_kernel(
    const float* __restrict__ x, const float* __restrict__ y,
    unsigned* __restrict__ mins) {
    __shared__ float4 tgtA[SEGLEN / 2];
    __shared__ float4 tgtB[SEGLEN / 2];

    const int dir = blockIdx.z;
    const int b = blockIdx.y;
    const int seg = blockIdx.x & (SEGS - 1);
    const int qb = blockIdx.x >> SEG_SHIFT;

    const float* pts = dir ? y : x;  // query set
    const float* oth = dir ? x : y;  // target set

    // stage one segment: one point per thread (SEGLEN <= BLOCK)
    if (threadIdx.x < SEGLEN) {
        const int p = threadIdx.x;
        const float* q = oth + ((size_t)b * NPTS + seg * SEGLEN + p) * 3;
        const float qx = q[0], qy = q[1], qz = q[2];
        const float sq = fmaf(qz, qz, fmaf(qy, qy, qx * qx));
        float* A = (float*)tgtA;
        float* Bv = (float*)tgtB;
        const int pi = p >> 1, par = p & 1;
        A[pi * 4 + par] = qx;
        A[pi * 4 + 2 + par] = qy;
        Bv[pi * 4 + par] = qz;
        Bv[pi * 4 + 2 + par] = sq;
    }

    // query points -> registers as packed splats (-2*p per component);
    // |p|^2 folded in at the end.
    v2f m2x[NQ], m2y[NQ], m2z[NQ];
    float sp[NQ], best[NQ];
    const int qbase = b * NPTS + qb * QPB + (int)threadIdx.x;
#pragma unroll
    for (int k = 0; k < NQ; ++k) {
        const float* p = pts + (size_t)(qbase + k * BLOCK) * 3;
        const float px = p[0], py = p[1], pz = p[2];
        m2x[k] = (v2f){-2.0f * px, -2.0f * px};
        m2y[k] = (v2f){-2.0f * py, -2.0f * py};
        m2z[k] = (v2f){-2.0f * pz, -2.0f * pz};
        sp[k] = fmaf(pz, pz, fmaf(py, py, px * px));
        best[k] = 3.0e38f;
    }

    __syncthreads();

#pragma unroll 2
    for (int j = 0; j < SEGLEN / 2; ++j) {
        const float4 A = tgtA[j];
        const float4 Bv = tgtB[j];
        const v2f qx2 = {A.x, A.y};
        const v2f qy2 = {A.z, A.w};
        const v2f qz2 = {Bv.x, Bv.y};
        const v2f sq2 = {Bv.z, Bv.w};
#pragma unroll
        for (int k = 0; k < NQ; ++k) {
            // ffp-contract=fast (HIP default) fuses these into v_pk_fma_f32
            v2f d = qx2 * m2x[k] + sq2;
            d = qy2 * m2y[k] + d;
            d = qz2 * m2z[k] + d;
            best[k] = fminf(fminf(best[k], d.x), d.y);  // v_min3_f32
        }
    }

    unsigned* om = mins + (size_t)(dir * BATCH + b) * NPTS + qb * QPB + threadIdx.x;
#pragma unroll
    for (int k = 0; k < NQ; ++k) {
        const float d = fmaxf(sp[k] + best[k], 0.0f);  // >=0: uint order == float order
        atomicMin(&om[k * BLOCK], __float_as_uint(d));
    }
}

// ---------------------------------------------------------------------------
// finalize: 64 blocks x 256 threads (R7-proven). Each block sums a 4 KB
// slice of mins (uint4, coalesced), reduces, atomicAdds partial * 1/(B*N)
// into out[0] (pre-zeroed). Block 0 / thread 0 adds the regularizer.
// ---------------------------------------------------------------------------
__global__ __launch_bounds__(256) void finalize_kernel(
    const unsigned* __restrict__ mins, const float* __restrict__ R,
    const float* __restrict__ S, const float* __restrict__ t,
    const float* __restrict__ R_gt, const float* __restrict__ S_gt,
    const float* __restrict__ t_gt, float* __restrict__ out) {
    const uint4* m4 = (const uint4*)mins;  // 2*B*N/4 = 16384 uint4s
    const int gid = blockIdx.x * 256 + (int)threadIdx.x;  // 0..16383
    const uint4 u = m4[gid];
    float v = (__uint_as_float(u.x) + __uint_as_float(u.y) +
               __uint_as_float(u.z) + __uint_as_float(u.w)) *
              (1.0f / (BATCH * NPTS));

    if (gid == 0) {
        float acc = 0.0f;
        for (int b = 0; b < BATCH; ++b)
            for (int i = 0; i < 3; ++i)
                for (int k = 0; k < 3; ++k) {
                    float s = 0.0f;
                    for (int j = 0; j < 3; ++j)
                        s += R_gt[b * 9 + j * 3 + i] * R[b * 9 + j * 3 + k];
                    s -= (i == k) ? 1.0f : 0.0f;
                    acc += s * s;
                }
        for (int d = 0; d < 3; ++d)  // jnp.diagonal(S, axis1=0, axis2=1)
            for (int a = 0; a < 3; ++a) {
                const float diff = S[d * 9 + d * 3 + a] - S_gt[d * 9 + d * 3 + a];
                acc += diff * diff;
            }
        for (int b = 0; b < BATCH; ++b)
            for (int k = 0; k < 3; ++k) {
                const float diff = t[b * 3 + k] - t_gt[b * 3 + k];
                acc += diff * diff;
            }
        v += acc;
    }

    // block reduction: 4 waves of 64
    for (int off = 32; off; off >>= 1) v += __shfl_down(v, off, 64);
    __shared__ float wsum[4];
    const int lane = threadIdx.x & 63;
    const int wave = threadIdx.x >> 6;
    if (lane == 0) wsum[wave] = v;
    __syncthreads();
    if (wave == 0) {
        v = (lane < 4) ? wsum[lane] : 0.0f;
        for (int off = 2; off; off >>= 1) v += __shfl_down(v, off, 64);
        if (lane == 0) atomicAdd(out, v);
    }
}

extern "C" void kernel_launch(void* const* d_in, const int* in_sizes, int n_in,
                              void* d_out, int out_size, void* d_ws, size_t ws_size,
                              hipStream_t stream) {
    const float* x    = (const float*)d_in[0];
    const float* y    = (const float*)d_in[1];
    const float* R    = (const float*)d_in[2];
    const float* S    = (const float*)d_in[3];
    const float* t    = (const float*)d_in[4];
    const float* R_gt = (const float*)d_in[5];
    const float* S_gt = (const float*)d_in[6];
    const float* t_gt = (const float*)d_in[7];
    float* out = (float*)d_out;
    unsigned* mins = (unsigned*)d_ws;  // 2*B*N uints = 256 KiB

    // init mins to 0xFFFFFFFF (uint max) for atomicMin; zero the scalar out.
    hipMemsetAsync(mins, 0xFF, (size_t)2 * BATCH * NPTS * sizeof(unsigned), stream);
    hipMemsetAsync(out, 0, sizeof(float), stream);

    chamfer_kernel<<<dim3(QBLOCKS * SEGS, BATCH, 2), dim3(BLOCK), 0, stream>>>(x, y, mins);

    finalize_kernel<<<dim3(2 * BATCH * NPTS / 4 / 256), dim3(BLOCK), 0, stream>>>(
        mins, R, S, t, R_gt, S_gt, t_gt, out);
}